// Round 4
// baseline (713.875 us; speedup 1.0000x reference)
//
#include <hip/hip_runtime.h>
#include <hip/hip_bf16.h>
#include <math.h>

#define HD 1024   // hidden
#define FD 4096   // ffn
#define NE 8      // experts
#define NT 2048   // tokens (B*S)
#define BM 128
#define BN 128
#define BK 32

// ---------------- ws layout (needs >= 80 MiB) ----------------
// counts @0, lists @1024 (64KB), route_w @66560 (16KB)
// xb    @ 1 MiB  : [NT][HD] bf16        (4 MiB)
// hmid  @ 8 MiB  : [2*NT][FD] bf16      (32 MiB)
// opair @48 MiB  : [2][2*NT][HD] f32    (32 MiB)
#define WS_LISTS   1024
#define WS_ROUTEW  (1024 + NE*NT*4)
#define WS_XB      ((size_t)1 << 20)
#define WS_HMID    ((size_t)8 << 20)
#define WS_OPAIR   ((size_t)48 << 20)

typedef __attribute__((ext_vector_type(8))) short bf16x8;   // MFMA A/B frag (4 VGPRs)
typedef __attribute__((ext_vector_type(4))) float f32x4;    // MFMA C/D frag

static __device__ __forceinline__ unsigned int pk_bf16(float a, float b) {
    __hip_bfloat162 h = __float22bfloat162_rn(make_float2(a, b));
    return *reinterpret_cast<unsigned int*>(&h);
}

// async 16B/lane global->LDS. LDS dest = l + lane*16 (wave-uniform l required).
static __device__ __forceinline__ void gll16(const void* g, void* l) {
    __builtin_amdgcn_global_load_lds(
        (const __attribute__((address_space(1))) unsigned int*)g,
        (__attribute__((address_space(3))) unsigned int*)l,
        16, 0, 0);
}

__global__ void prep_kernel(const float* __restrict__ x, unsigned short* __restrict__ xb,
                            int* __restrict__ counts) {
    int idx = blockIdx.x * 256 + threadIdx.x;   // 524288 threads: 4 floats each
    if (idx < NE) counts[idx] = 0;
    float4 v = *(const float4*)(x + (size_t)idx * 4);
    *(uint2*)(xb + (size_t)idx * 4) = make_uint2(pk_bf16(v.x, v.y), pk_bf16(v.z, v.w));
}

__global__ __launch_bounds__(128)
void router_kernel(const float* __restrict__ x, const float* __restrict__ Wr,
                   int* __restrict__ counts, int* __restrict__ lists,
                   float* __restrict__ route_w) {
    int t = blockIdx.x;
    int tid = threadIdx.x;
    float acc[NE];
#pragma unroll
    for (int e = 0; e < NE; e++) acc[e] = 0.f;
    const float* xt = x + (size_t)t * HD;
    for (int h = tid; h < HD; h += 128) {
        float xv = xt[h];
#pragma unroll
        for (int e = 0; e < NE; e++) acc[e] += xv * Wr[e * HD + h];
    }
    __shared__ float red[NE][128];
#pragma unroll
    for (int e = 0; e < NE; e++) red[e][tid] = acc[e];
    __syncthreads();
    for (int s = 64; s > 0; s >>= 1) {
        if (tid < s) {
#pragma unroll
            for (int e = 0; e < NE; e++) red[e][tid] += red[e][tid + s];
        }
        __syncthreads();
    }
    if (tid == 0) {
        int i0 = 0; float l0 = red[0][0];
        for (int e = 1; e < NE; e++) { float v = red[e][0]; if (v > l0) { l0 = v; i0 = e; } }
        int i1 = -1; float l1 = -3.0e38f;
        for (int e = 0; e < NE; e++) {
            if (e == i0) continue;
            float v = red[e][0]; if (v > l1) { l1 = v; i1 = e; }
        }
        float w0 = 1.f / (1.f + expf(l1 - l0));
        float w1 = 1.f - w0;
        int s0 = atomicAdd(&counts[i0], 1);
        lists[i0 * NT + s0] = t * 2;
        route_w[t * 2] = w0;
        int s1 = atomicAdd(&counts[i1], 1);
        lists[i1 * NT + s1] = t * 2 + 1;
        route_w[t * 2 + 1] = w1;
    }
}

// ---- B staging: coalesced fp32 [k][n] loads -> cvt_pk_bf16 -> LDS [n][k] stride-40-short.
// Thread coords: kp=(tid&15)*2 (k-pair base), kpr=tid&15 (uint word in row), nqa=tid>>4.
// Covers per call: cols nqa*4..+3 and (nqa+16)*4..+3, k rows kp,kp+1  == full 32x128 tile.
#define LOADB_PAIR(buf, base, stride, h)  do {                                   \
    const float* _p = (base) + (size_t)(h) * (stride);                           \
    buf[0] = *(const float4*)(_p);          buf[1] = *(const float4*)(_p + (stride)); \
    buf[2] = *(const float4*)(_p + 64);     buf[3] = *(const float4*)(_p + (stride) + 64); \
} while (0)

#define PK4(udst, noff, va, vb)  do {                                            \
    udst[((noff) + 0) * 20 + kpr] = pk_bf16(va.x, vb.x);                         \
    udst[((noff) + 1) * 20 + kpr] = pk_bf16(va.y, vb.y);                         \
    udst[((noff) + 2) * 20 + kpr] = pk_bf16(va.z, vb.z);                         \
    udst[((noff) + 3) * 20 + kpr] = pk_bf16(va.w, vb.w);                         \
} while (0)

// GEMM1: gathered xb rows @ W1[e],W3[e] (fp32 [k][n], converted in-kernel), SwiGLU -> hmid bf16.
// 128x128x32 tile, 4 waves x (64x64). A via global_load_lds; B via fused cvt+transpose staging
// with cross-iter VGPR double-buffer prefetch. XCD-grouped grid for weight L2 reuse.
__global__ __launch_bounds__(256, 2)
void gemm1_kernel(const unsigned short* __restrict__ xb, const float* __restrict__ W1,
                  const float* __restrict__ W3,
                  const int* __restrict__ counts, const int* __restrict__ lists,
                  unsigned short* __restrict__ hmid) {
    int xcd = blockIdx.x;                 // 0..7
    int y = blockIdx.y;                   // 0..511
    int en = xcd + 8 * (y >> 4);          // (e, nblk): 4 active m-neighbors share xcd
    int mblk = y & 15;
    int e = en >> 5;
    int nblk = en & 31;
    int cnt = counts[e];
    int m0 = mblk * BM;
    if (m0 >= cnt) return;
    int n0 = nblk * BN;
    const float* W1e = W1 + (size_t)e * HD * FD;
    const float* W3e = W3 + (size_t)e * HD * FD;

    __shared__ __align__(16) unsigned short As[128 * 32];    // [m][k] stride 32
    __shared__ __align__(16) unsigned short B1s[128 * 40];   // [n][k] stride 40 (pad)
    __shared__ __align__(16) unsigned short B3s[128 * 40];
    __shared__ int rp_s[128];

    int tid = threadIdx.x;
    if (tid < 128) {
        int m = m0 + tid;
        rp_s[tid] = (m < cnt) ? lists[e * NT + m] : lists[e * NT];
    }
    __syncthreads();

    const int w = tid >> 6;
    const int lane = tid & 63;
    const int srow = lane >> 2;
    const int schunk = lane & 3;

    const unsigned short* gA[2];
    unsigned short* lA[2];
#pragma unroll
    for (int q = 0; q < 2; q++) {
        int row = w * 32 + q * 16 + srow;
        gA[q] = xb + (size_t)(rp_s[row] >> 1) * HD + schunk * 8;
        lA[q] = &As[(w * 32 + q * 16) * 32];
    }

    const int kp  = (tid & 15) * 2;
    const int kpr = tid & 15;
    const int nqa = tid >> 4;
    const float* pB1 = W1e + (size_t)kp * FD + n0 + nqa * 4;
    const float* pB3 = W3e + (size_t)kp * FD + n0 + nqa * 4;
    unsigned int* uB1 = (unsigned int*)B1s;
    unsigned int* uB3 = (unsigned int*)B3s;

    const int wr = w >> 1, wc = w & 1;
    const int lm = lane & 15, lg = lane >> 4;

    f32x4 zf = {0.f, 0.f, 0.f, 0.f};
    f32x4 accG[4][4], accU[4][4];
#pragma unroll
    for (int i = 0; i < 4; i++)
#pragma unroll
        for (int j = 0; j < 4; j++) { accG[i][j] = zf; accU[i][j] = zf; }

    float4 bufA[8], bufB[8];
    LOADB_PAIR(bufA,       pB1, FD, 0);
    LOADB_PAIR((bufA + 4), pB3, FD, 0);

#define G1_STEP(CUR, NXT, H0)  do {                                              \
    __syncthreads();  /* prev frag reads done */                                 \
    gll16(gA[0] + (H0), lA[0]); gll16(gA[1] + (H0), lA[1]);                      \
    if ((H0) + BK < HD) {                                                        \
        LOADB_PAIR(NXT,       pB1, FD, (H0) + BK);                               \
        LOADB_PAIR((NXT + 4), pB3, FD, (H0) + BK);                               \
    }                                                                            \
    PK4(uB1, nqa * 4,        CUR[0], CUR[1]);                                    \
    PK4(uB1, (nqa + 16) * 4, CUR[2], CUR[3]);                                    \
    PK4(uB3, nqa * 4,        CUR[4], CUR[5]);                                    \
    PK4(uB3, (nqa + 16) * 4, CUR[6], CUR[7]);                                    \
    __syncthreads();  /* staging complete */                                     \
    {                                                                            \
        bf16x8 af[4], b1f[4], b3f[4];                                            \
        _Pragma("unroll")                                                        \
        for (int i = 0; i < 4; i++)                                              \
            af[i] = *(const bf16x8*)&As[(wr * 64 + i * 16 + lm) * 32 + lg * 8];  \
        _Pragma("unroll")                                                        \
        for (int j = 0; j < 4; j++) {                                            \
            b1f[j] = *(const bf16x8*)&B1s[(wc * 64 + j * 16 + lm) * 40 + lg * 8];\
            b3f[j] = *(const bf16x8*)&B3s[(wc * 64 + j * 16 + lm) * 40 + lg * 8];\
        }                                                                        \
        _Pragma("unroll")                                                        \
        for (int i = 0; i < 4; i++)                                              \
            _Pragma("unroll")                                                    \
            for (int j = 0; j < 4; j++) {                                        \
                accG[i][j] = __builtin_amdgcn_mfma_f32_16x16x32_bf16(af[i], b1f[j], accG[i][j], 0, 0, 0); \
                accU[i][j] = __builtin_amdgcn_mfma_f32_16x16x32_bf16(af[i], b3f[j], accU[i][j], 0, 0, 0); \
            }                                                                    \
    }                                                                            \
} while (0)

    for (int h0 = 0; h0 < HD; h0 += 2 * BK) {
        G1_STEP(bufA, bufB, h0);
        G1_STEP(bufB, bufA, h0 + BK);
    }
#undef G1_STEP

    // epilogue: silu(gate)*up -> bf16. C/D: col(n)=lane&15, row(m)=lg*4+reg (validated R2/R3)
#pragma unroll
    for (int i = 0; i < 4; i++) {
#pragma unroll
        for (int r = 0; r < 4; r++) {
            int ml = wr * 64 + i * 16 + lg * 4 + r;
            int m = m0 + ml;
            if (m < cnt) {
                int p = rp_s[ml];
                unsigned short* hrow = hmid + (size_t)p * FD + n0 + wc * 64 + lm;
#pragma unroll
                for (int j = 0; j < 4; j++) {
                    float g = accG[i][j][r];
                    float u = accU[i][j][r];
                    float v = (g / (1.f + expf(-g))) * u;
                    __hip_bfloat16 hb = __float2bfloat16(v);
                    hrow[j * 16] = *reinterpret_cast<unsigned short*>(&hb);
                }
            }
        }
    }
}

// GEMM2: gathered hmid rows @ W2[e] (fp32 [k=f][n=h], converted in-kernel),
// split-K=2, plain stores to opair.
__global__ __launch_bounds__(256, 2)
void gemm2_kernel(const unsigned short* __restrict__ hmid, const float* __restrict__ W2,
                  const int* __restrict__ counts, const int* __restrict__ lists,
                  float* __restrict__ opair) {
    int xcd = blockIdx.x;                 // 0..7
    int y = blockIdx.y;                   // 0..255
    int grp = xcd + 8 * (y >> 4);         // (ks, e, nblk)
    int mblk = y & 15;
    int ks = grp >> 6;
    int rest = grp & 63;
    int e = rest >> 3;
    int nblk = rest & 7;
    int cnt = counts[e];
    int m0 = mblk * BM;
    if (m0 >= cnt) return;
    int n0 = nblk * BN;
    const float* W2e = W2 + (size_t)e * FD * HD;

    __shared__ __align__(16) unsigned short As[128 * 32];
    __shared__ __align__(16) unsigned short Bs[128 * 40];
    __shared__ int rp_s[128];

    int tid = threadIdx.x;
    if (tid < 128) {
        int m = m0 + tid;
        rp_s[tid] = (m < cnt) ? lists[e * NT + m] : lists[e * NT];
    }
    __syncthreads();

    const int w = tid >> 6;
    const int lane = tid & 63;
    const int srow = lane >> 2;
    const int schunk = lane & 3;

    const unsigned short* gA[2];
    unsigned short* lA[2];
#pragma unroll
    for (int q = 0; q < 2; q++) {
        int row = w * 32 + q * 16 + srow;
        gA[q] = hmid + (size_t)rp_s[row] * FD + schunk * 8;
        lA[q] = &As[(w * 32 + q * 16) * 32];
    }

    const int kp  = (tid & 15) * 2;
    const int kpr = tid & 15;
    const int nqa = tid >> 4;
    const float* pB2 = W2e + (size_t)kp * HD + n0 + nqa * 4;
    unsigned int* uB = (unsigned int*)Bs;

    const int wr = w >> 1, wc = w & 1;
    const int lm = lane & 15, lg = lane >> 4;

    f32x4 zf = {0.f, 0.f, 0.f, 0.f};
    f32x4 acc[4][4];
#pragma unroll
    for (int i = 0; i < 4; i++)
#pragma unroll
        for (int j = 0; j < 4; j++) acc[i][j] = zf;

    const int f_begin = ks * (FD / 2);
    const int f_end   = f_begin + FD / 2;

    float4 bufA[4], bufB[4];
    LOADB_PAIR(bufA, pB2, HD, f_begin);

#define G2_STEP(CUR, NXT, F0)  do {                                              \
    __syncthreads();                                                             \
    gll16(gA[0] + (F0), lA[0]); gll16(gA[1] + (F0), lA[1]);                      \
    if ((F0) + BK < f_end) { LOADB_PAIR(NXT, pB2, HD, (F0) + BK); }              \
    PK4(uB, nqa * 4,        CUR[0], CUR[1]);                                     \
    PK4(uB, (nqa + 16) * 4, CUR[2], CUR[3]);                                     \
    __syncthreads();                                                             \
    {                                                                            \
        bf16x8 af[4], bf[4];                                                     \
        _Pragma("unroll")                                                        \
        for (int i = 0; i < 4; i++)                                              \
            af[i] = *(const bf16x8*)&As[(wr * 64 + i * 16 + lm) * 32 + lg * 8];  \
        _Pragma("unroll")                                                        \
        for (int j = 0; j < 4; j++)                                              \
            bf[j] = *(const bf16x8*)&Bs[(wc * 64 + j * 16 + lm) * 40 + lg * 8];  \
        _Pragma("unroll")                                                        \
        for (int i = 0; i < 4; i++)                                              \
            _Pragma("unroll")                                                    \
            for (int j = 0; j < 4; j++)                                          \
                acc[i][j] = __builtin_amdgcn_mfma_f32_16x16x32_bf16(af[i], bf[j], acc[i][j], 0, 0, 0); \
    }                                                                            \
} while (0)

    for (int f0 = f_begin; f0 < f_end; f0 += 2 * BK) {
        G2_STEP(bufA, bufB, f0);
        G2_STEP(bufB, bufA, f0 + BK);
    }
#undef G2_STEP

#pragma unroll
    for (int i = 0; i < 4; i++) {
#pragma unroll
        for (int r = 0; r < 4; r++) {
            int ml = wr * 64 + i * 16 + lg * 4 + r;
            int m = m0 + ml;
            if (m < cnt) {
                int p = rp_s[ml];
                float* op = opair + ((size_t)ks * (2 * NT) + p) * HD + n0 + wc * 64 + lm;
#pragma unroll
                for (int j = 0; j < 4; j++) op[j * 16] = acc[i][j][r];
            }
        }
    }
}

// out[tok] = w0*(o_ks0[2t]+o_ks1[2t]) + w1*(o_ks0[2t+1]+o_ks1[2t+1])
__global__ __launch_bounds__(256)
void combine_kernel(const float* __restrict__ opair, const float* __restrict__ route_w,
                    float* __restrict__ out) {
    int idx = blockIdx.x * 256 + threadIdx.x;   // 524288
    int tok = idx >> 8;
    int hc = (idx & 255) * 4;
    const float* o0 = opair;
    const float* o1 = opair + (size_t)(2 * NT) * HD;
    size_t r0 = (size_t)(2 * tok) * HD + hc;
    size_t r1 = (size_t)(2 * tok + 1) * HD + hc;
    float w0 = route_w[2 * tok], w1 = route_w[2 * tok + 1];
    float4 a = *(const float4*)(o0 + r0);
    float4 b = *(const float4*)(o1 + r0);
    float4 c = *(const float4*)(o0 + r1);
    float4 d = *(const float4*)(o1 + r1);
    float4 r;
    r.x = w0 * (a.x + b.x) + w1 * (c.x + d.x);
    r.y = w0 * (a.y + b.y) + w1 * (c.y + d.y);
    r.z = w0 * (a.z + b.z) + w1 * (c.z + d.z);
    r.w = w0 * (a.w + b.w) + w1 * (c.w + d.w);
    *(float4*)(out + (size_t)tok * HD + hc) = r;
}

extern "C" void kernel_launch(void* const* d_in, const int* in_sizes, int n_in,
                              void* d_out, int out_size, void* d_ws, size_t ws_size,
                              hipStream_t stream) {
    const float* x  = (const float*)d_in[0];  // [T, H]
    const float* Wr = (const float*)d_in[1];  // [E, H]
    const float* W1 = (const float*)d_in[2];  // [E, H, F]
    const float* W2 = (const float*)d_in[3];  // [E, F, H]
    const float* W3 = (const float*)d_in[4];  // [E, H, F]
    float* out = (float*)d_out;               // [T, H]

    char* ws = (char*)d_ws;
    int*   counts  = (int*)(ws);
    int*   lists   = (int*)(ws + WS_LISTS);
    float* route_w = (float*)(ws + WS_ROUTEW);
    unsigned short* xb   = (unsigned short*)(ws + WS_XB);
    unsigned short* hmid = (unsigned short*)(ws + WS_HMID);
    float* opair = (float*)(ws + WS_OPAIR);

    hipLaunchKernelGGL(prep_kernel, dim3(2048), dim3(256), 0, stream, x, xb, counts);
    hipLaunchKernelGGL(router_kernel, dim3(NT), dim3(128), 0, stream,
                       x, Wr, counts, lists, route_w);
    hipLaunchKernelGGL(gemm1_kernel, dim3(8, 512), dim3(256), 0, stream,
                       xb, W1, W3, counts, lists, hmid);
    hipLaunchKernelGGL(gemm2_kernel, dim3(8, 256), dim3(256), 0, stream,
                       hmid, W2, counts, lists, opair);
    hipLaunchKernelGGL(combine_kernel, dim3(2048), dim3(256), 0, stream,
                       opair, route_w, out);
}